// Round 7
// baseline (264.778 us; speedup 1.0000x reference)
//
#include <hip/hip_runtime.h>

#define T_LEN 200
#define F_IN  32
#define TC    4                 // timesteps per chunk; 200 = 50 * 4
#define NCH   (T_LEN / TC)
#define PSTR  132               // P batch stride (floats): 4t*32 + 4 pad
#define PBUF  (16 * PSTR)
#define ZSTR  200

#define QP(a,b,c,d) ((a)|((b)<<2)|((c)<<4)|((d)<<6))
#define DPP_HM 0x141            // row_half_mirror: lane^7 within 8

typedef short  bf16x8  __attribute__((ext_vector_type(8)));
typedef float  floatx4 __attribute__((ext_vector_type(4)));

template <int CTRL>
__device__ __forceinline__ float dppf(float v) {
    return __int_as_float(__builtin_amdgcn_update_dpp(
        0, __float_as_int(v), CTRL, 0xF, 0xF, true));
}
__device__ __forceinline__ void bfsplit(float x, short& hi, short& lo) {
    unsigned u = __float_as_uint(x);
    unsigned short h = (unsigned short)(u >> 16);
    float r = x - __uint_as_float(((unsigned)h) << 16);
    hi = (short)h;
    lo = (short)(__float_as_uint(r) >> 16);
}

__launch_bounds__(64, 1)
__global__ void mono_lstm_kernel(const float* __restrict__ x,
                                 const float* __restrict__ z0,
                                 const float* __restrict__ W_ih,
                                 const float* __restrict__ W_hh,
                                 const float* __restrict__ b_ih,
                                 const float* __restrict__ b_hh,
                                 const float* __restrict__ W1,
                                 const float* __restrict__ b1,
                                 const float* __restrict__ W2,
                                 const float* __restrict__ b2,
                                 float* __restrict__ out) {
    __shared__ float pls[2 * PBUF];     // P double buffer, 16 batches
    __shared__ float zls[16 * ZSTR];    // z output staging

    const int lane = threadIdx.x;       // single wave per block
    const int bl   = lane >> 3;         // batch-within-octet 0..7
    const int j    = lane & 7;          // hidden unit owned by this lane
    const int bg   = blockIdx.x * 16;   // 16 batches per block (2 octets)

    const float L2E = 1.4426950408889634f;
    const float NSC = -L2E;             // i,f,o rows (exp2(-u) form)
    const float NSG = -2.0f * L2E;      // g rows (tanh u = 2*sig(2u)-1)

    // ---- recurrence weights (R5-validated, xor-gather order, prescaled) ----
    const int ri = j, rf = 8 + j, rg_ = 16 + j, ro = 24 + j;
    float whi[8], whf[8], whg[8], who[8];
#pragma unroll
    for (int k = 0; k < 8; ++k) {
        whi[k] = W_hh[ri * 8 + (j ^ k)] * NSC;
        whf[k] = W_hh[rf * 8 + (j ^ k)] * NSC;
        whg[k] = W_hh[rg_ * 8 + (j ^ k)] * NSG;
        who[k] = W_hh[ro * 8 + (j ^ k)] * NSC;
    }
    const float wzi = W_ih[ri * 33 + 32] * NSC;
    const float wzf = W_ih[rf * 33 + 32] * NSC;
    const float wzg = W_ih[rg_ * 33 + 32] * NSG;
    const float wzo = W_ih[ro * 33 + 32] * NSC;

    // ---- distributed head (R4-validated): lane j<5 owns W1 row j ----
    float w1r[8];
    float b1r = 0.f, w2r = 0.f;
#pragma unroll
    for (int k = 0; k < 8; ++k) w1r[k] = 0.f;
    if (j < 5) {
#pragma unroll
        for (int k = 0; k < 8; ++k) w1r[k] = W1[j * 8 + (j ^ k)];
        b1r = b1[j];
        w2r = W2[j];
    }
    const float b2v = b2[0];

    // ---- MFMA B fragments (R5-validated): tile0 rows 0..15, tile1 16..31 ----
    const int n  = lane & 15;
    const int kq = lane >> 4;
    const float sc0 = NSC;
    const float sc1 = (n < 8) ? NSG : NSC;
    bf16x8 Bh0, Bl0, Bh1, Bl1;
#pragma unroll
    for (int i = 0; i < 8; ++i) {
        const int k = kq * 8 + i;
        short h, l;
        bfsplit(W_ih[n * 33 + k] * sc0, h, l);        Bh0[i] = h; Bl0[i] = l;
        bfsplit(W_ih[(16 + n) * 33 + k] * sc1, h, l); Bh1[i] = h; Bl1[i] = l;
    }
    const float bias0 = (b_ih[n] + b_hh[n]) * sc0;
    const float bias1 = (b_ih[16 + n] + b_hh[16 + n]) * sc1;

    // A-fragment source (R5-validated mapping): m=lane&15 -> (batch m>>1, t-parity m&1)
    const int am = lane & 15;
    const float* xa0 = x + ((size_t)(bg + (am >> 1)) * T_LEN + (am & 1)) * F_IN + kq * 8;
    const float* xa1 = xa0 + (size_t)8 * T_LEN * F_IN;   // octet 1

    float4 rgv[2][4];
    auto load_x = [&](int ch) {
#pragma unroll
        for (int s = 0; s < 2; ++s) {
            const float* p0 = xa0 + (size_t)(ch * TC + 2 * s) * F_IN;
            const float* p1 = xa1 + (size_t)(ch * TC + 2 * s) * F_IN;
            rgv[0][2 * s]     = *(const float4*)p0;
            rgv[0][2 * s + 1] = *(const float4*)(p0 + 4);
            rgv[1][2 * s]     = *(const float4*)p1;
            rgv[1][2 * s + 1] = *(const float4*)(p1 + 4);
        }
    };
    auto mfma_phase = [&](int o, int buf) {
#pragma unroll
        for (int s = 0; s < 2; ++s) {
            const float xv[8] = {rgv[o][2*s].x, rgv[o][2*s].y, rgv[o][2*s].z, rgv[o][2*s].w,
                                 rgv[o][2*s+1].x, rgv[o][2*s+1].y, rgv[o][2*s+1].z, rgv[o][2*s+1].w};
            bf16x8 Ah, Al;
#pragma unroll
            for (int i = 0; i < 8; ++i) {
                short h, l;
                bfsplit(xv[i], h, l);
                Ah[i] = h; Al[i] = l;
            }
            floatx4 a0 = {bias0, bias0, bias0, bias0};
            floatx4 a1 = {bias1, bias1, bias1, bias1};
            a0 = __builtin_amdgcn_mfma_f32_16x16x32_bf16(Ah, Bh0, a0, 0, 0, 0);
            a0 = __builtin_amdgcn_mfma_f32_16x16x32_bf16(Al, Bh0, a0, 0, 0, 0);
            a0 = __builtin_amdgcn_mfma_f32_16x16x32_bf16(Ah, Bl0, a0, 0, 0, 0);
            a1 = __builtin_amdgcn_mfma_f32_16x16x32_bf16(Ah, Bh1, a1, 0, 0, 0);
            a1 = __builtin_amdgcn_mfma_f32_16x16x32_bf16(Al, Bh1, a1, 0, 0, 0);
            a1 = __builtin_amdgcn_mfma_f32_16x16x32_bf16(Ah, Bl1, a1, 0, 0, 0);
#pragma unroll
            for (int reg = 0; reg < 4; ++reg) {
                const int mr = (lane >> 4) * 4 + reg;      // C/D row
                const int b16 = o * 8 + (mr >> 1);
                const int tt  = 2 * s + (mr & 1);
                pls[buf * PBUF + b16 * PSTR + tt * 32 + n]      = a0[reg];
                pls[buf * PBUF + b16 * PSTR + tt * 32 + 16 + n] = a1[reg];
            }
        }
    };

    // ---- prologue ----
    load_x(0);
    mfma_phase(0, 0);
    mfma_phase(1, 0);
    load_x(1);

    float ha[2][8];
#pragma unroll
    for (int s = 0; s < 2; ++s)
#pragma unroll
        for (int k = 0; k < 8; ++k) ha[s][k] = 0.f;
    float cst[2] = {0.f, 0.f};
    float zst[2] = {z0[bg + bl], z0[bg + 8 + bl]};

    for (int ch = 0; ch < NCH; ++ch) {
        // pv for current chunk (written by previous iteration's mfma_phase)
        float pvi[2][TC], pvf[2][TC], pvg[2][TC], pvo[2][TC];
#pragma unroll
        for (int s = 0; s < 2; ++s) {
            const int base = (ch & 1) * PBUF + (s * 8 + bl) * PSTR;
#pragma unroll
            for (int t = 0; t < TC; ++t) {
                pvi[s][t] = pls[base + t * 32 + j];
                pvf[s][t] = pls[base + t * 32 + 8 + j];
                pvg[s][t] = pls[base + t * 32 + 16 + j];
                pvo[s][t] = pls[base + t * 32 + 24 + j];
            }
        }

#pragma unroll
        for (int t = 0; t < TC; ++t) {
#pragma unroll
            for (int s = 0; s < 2; ++s) {
                const float z = zst[s];
                float mi = fmaf(whi[0], ha[s][0], fmaf(whi[1], ha[s][1],
                           fmaf(whi[2], ha[s][2], fmaf(whi[3], ha[s][3], pvi[s][t]))));
                float ni = fmaf(whi[4], ha[s][4], fmaf(whi[5], ha[s][5],
                           fmaf(whi[6], ha[s][6], whi[7] * ha[s][7])));
                float mf = fmaf(whf[0], ha[s][0], fmaf(whf[1], ha[s][1],
                           fmaf(whf[2], ha[s][2], fmaf(whf[3], ha[s][3], pvf[s][t]))));
                float nf = fmaf(whf[4], ha[s][4], fmaf(whf[5], ha[s][5],
                           fmaf(whf[6], ha[s][6], whf[7] * ha[s][7])));
                float mg = fmaf(whg[0], ha[s][0], fmaf(whg[1], ha[s][1],
                           fmaf(whg[2], ha[s][2], fmaf(whg[3], ha[s][3], pvg[s][t]))));
                float ng = fmaf(whg[4], ha[s][4], fmaf(whg[5], ha[s][5],
                           fmaf(whg[6], ha[s][6], whg[7] * ha[s][7])));
                float mo = fmaf(who[0], ha[s][0], fmaf(who[1], ha[s][1],
                           fmaf(who[2], ha[s][2], fmaf(who[3], ha[s][3], pvo[s][t]))));
                float no = fmaf(who[4], ha[s][4], fmaf(who[5], ha[s][5],
                           fmaf(who[6], ha[s][6], who[7] * ha[s][7])));

                const float ai = fmaf(wzi, z, mi + ni);
                const float af = fmaf(wzf, z, mf + nf);
                const float ag = fmaf(wzg, z, mg + ng);
                const float ao = fmaf(wzo, z, mo + no);

                const float si = __builtin_amdgcn_rcpf(1.0f + __builtin_amdgcn_exp2f(ai));
                const float sf = __builtin_amdgcn_rcpf(1.0f + __builtin_amdgcn_exp2f(af));
                const float sg = __builtin_amdgcn_rcpf(1.0f + __builtin_amdgcn_exp2f(ag));
                const float so = __builtin_amdgcn_rcpf(1.0f + __builtin_amdgcn_exp2f(ao));
                const float tg = fmaf(2.0f, sg, -1.0f);      // tanh(g)

                const float cn = fmaf(sf, cst[s], si * tg);
                cst[s] = cn;
                const float ec = __builtin_amdgcn_exp2f(cn * (-2.0f * L2E));
                const float tc = fmaf(2.0f, __builtin_amdgcn_rcpf(1.0f + ec), -1.0f);
                const float hn = so * tc;                    // h_j

                // gather h_{j^k}: pure DPP within the 8-group (R5-validated)
                ha[s][0] = hn;
                ha[s][1] = dppf<QP(1, 0, 3, 2)>(hn);
                ha[s][2] = dppf<QP(2, 3, 0, 1)>(hn);
                ha[s][3] = dppf<QP(3, 2, 1, 0)>(hn);
                const float t7 = dppf<DPP_HM>(hn);
                ha[s][7] = t7;
                ha[s][4] = dppf<QP(3, 2, 1, 0)>(t7);
                ha[s][5] = dppf<QP(2, 3, 0, 1)>(t7);
                ha[s][6] = dppf<QP(1, 0, 3, 2)>(t7);

                // distributed head (R4-validated): d_j on lane j, reduce over 8
                float d0 = fmaf(w1r[0], ha[s][0], fmaf(w1r[2], ha[s][2],
                           fmaf(w1r[4], ha[s][4], fmaf(w1r[6], ha[s][6], b1r))));
                float d1 = fmaf(w1r[1], ha[s][1], fmaf(w1r[3], ha[s][3],
                           fmaf(w1r[5], ha[s][5], w1r[7] * ha[s][7])));
                const float d = fmaxf(d0 + d1, 0.0f);
                float r = w2r * d;
                r += dppf<QP(1, 0, 3, 2)>(r);
                r += dppf<QP(2, 3, 0, 1)>(r);
                r += dppf<DPP_HM>(r);
                zst[s] = z + fmaxf(r + b2v, 0.0f);

                if (j == t) zls[(s * 8 + bl) * ZSTR + ch * TC + t] = zst[s];
            }
        }

        if (ch + 1 < NCH) {
            mfma_phase(0, (ch + 1) & 1);         // P(ch+1) from rgv
            mfma_phase(1, (ch + 1) & 1);
            if (ch + 2 < NCH) load_x(ch + 2);
        }
    }

    // coalesced output store: 16 batches x 50 float4
    __builtin_amdgcn_s_waitcnt(0);
#pragma unroll
    for (int it = 0; it < 13; ++it) {
        const int idx = lane + it * 64;
        if (idx < 16 * (T_LEN / 4)) {
            const int bb = idx / 50, rem = idx - bb * 50;
            *(float4*)&out[(size_t)(bg + bb) * T_LEN + rem * 4] =
                *(const float4*)&zls[bb * ZSTR + rem * 4];
        }
    }
}

extern "C" void kernel_launch(void* const* d_in, const int* in_sizes, int n_in,
                              void* d_out, int out_size, void* d_ws, size_t ws_size,
                              hipStream_t stream) {
    const float* x    = (const float*)d_in[0];
    const float* z0   = (const float*)d_in[1];
    const float* W_ih = (const float*)d_in[2];
    const float* W_hh = (const float*)d_in[3];
    const float* b_ih = (const float*)d_in[4];
    const float* b_hh = (const float*)d_in[5];
    const float* W1   = (const float*)d_in[6];
    const float* b1   = (const float*)d_in[7];
    const float* W2   = (const float*)d_in[8];
    const float* b2   = (const float*)d_in[9];
    float* out = (float*)d_out;

    const int B = in_sizes[1];
    dim3 grid(B / 16), block(64);
    hipLaunchKernelGGL(mono_lstm_kernel, grid, block, 0, stream,
                       x, z0, W_ih, W_hh, b_ih, b_hh, W1, b1, W2, b2, out);
}